// Round 4
// baseline (673.306 us; speedup 1.0000x reference)
//
#include <hip/hip_runtime.h>
#include <hip/hip_bf16.h>
#include <math.h>

#define B_   64
#define T_   32
#define S_   31      // scan steps = T-1
#define V_   10000
#define E_   300
#define H_   256
#define F_   4096
#define G4   1024    // 4*H
#define HE   556     // H+E
#define MPAD 2048    // S_*B_ = 1984 padded to 2048
#define NPAD 10112   // V padded to 79*128
#define START_ID 1
#define HP   264     // hA LDS pitch (bf16 elems): 264*2=528 B, breaks bank aliasing
#define GP   1028    // gs LDS pitch (f32 elems)

typedef __bf16 bf16x8 __attribute__((ext_vector_type(8)));
typedef float  f32x4  __attribute__((ext_vector_type(4)));

__device__ __forceinline__ float bf16bits_to_f(unsigned int u) {
    union { unsigned int i; float f; } c; c.i = u; return c.f;
}
__device__ __forceinline__ unsigned short f_to_bf16bits(float f) {
    union { float f; unsigned int i; } c; c.f = f;
    unsigned int r = c.i + 0x7fffu + ((c.i >> 16) & 1);   // RNE
    return (unsigned short)(r >> 16);
}
__device__ __forceinline__ float sigm(float x) { return 1.f / (1.f + __expf(-x)); }
__device__ __forceinline__ float tanh_fast(float x) { return 1.f - 2.f / (__expf(2.f * x) + 1.f); }

// ---------------- prep: fc2_w->bf16 (pad rows zeroed), zero Hs pad rows,
// pack w_hh into MFMA-B-fragment order (bf16), one-hot rows at t=0.
// wbf frag (n_tg,k_t): lane(quad,l16) holds w_hh[n_tg*16+l16][k_t*32+quad*8 .. +8]
__global__ void k_prep(const float* __restrict__ fc2_w, const float* __restrict__ w_hh,
                       __hip_bfloat16* __restrict__ fc2bf,
                       __hip_bfloat16* __restrict__ Hs,
                       unsigned short* __restrict__ wbf,
                       float* __restrict__ out) {
    size_t i = (size_t)blockIdx.x * 256 + threadIdx.x;   // < NPAD*H_ = 2,588,672
    float v = (i < (size_t)V_ * H_) ? fc2_w[i] : 0.f;
    fc2bf[i] = __float2bfloat16(v);
    if (i < (size_t)(MPAD - S_ * B_) * H_)
        Hs[(size_t)S_ * B_ * H_ + i] = __float2bfloat16(0.f);
    if (i < 64 * 8 * 64) {                               // 32768 B-frag chunks of 16B
        int lane = (int)(i & 63), k_t = (int)((i >> 6) & 7), n_tg = (int)(i >> 9);
        int quad = lane >> 4, l16 = lane & 15;
        const float* src = w_hh + (size_t)(n_tg * 16 + l16) * H_ + k_t * 32 + quad * 8;
        float4 a0 = *(const float4*)src;
        float4 a1 = *(const float4*)(src + 4);
        union { unsigned short s[8]; uint4 u; } pk;
        pk.s[0] = f_to_bf16bits(a0.x); pk.s[1] = f_to_bf16bits(a0.y);
        pk.s[2] = f_to_bf16bits(a0.z); pk.s[3] = f_to_bf16bits(a0.w);
        pk.s[4] = f_to_bf16bits(a1.x); pk.s[5] = f_to_bf16bits(a1.y);
        pk.s[6] = f_to_bf16bits(a1.z); pk.s[7] = f_to_bf16bits(a1.w);
        *(uint4*)(wbf + i * 8) = pk.u;
    }
    if (i < (size_t)B_ * V_) {                           // one-hot t=0 rows
        int b = (int)(i / V_), v0 = (int)(i - (size_t)b * V_);
        out[(size_t)b * T_ * V_ + v0] = (v0 == START_ID) ? 1.f : 0.f;
    }
}

// ---------------- Xp = X @ fc1_w.T + fc1_b   (64 x 256)
__global__ void k_xp(const float* __restrict__ X, const float* __restrict__ fc1_w,
                     const float* __restrict__ fc1_b, float* __restrict__ Xp) {
    __shared__ __align__(16) float xs[F_];
    int b = blockIdx.x;
    const float4* xrow = (const float4*)(X + (size_t)b * F_);
    for (int i = threadIdx.x; i < F_ / 4; i += 256) ((float4*)xs)[i] = xrow[i];
    __syncthreads();
    int k = threadIdx.x;
    const float4* w = (const float4*)(fc1_w + (size_t)k * F_);
    float acc = 0.f;
    #pragma unroll 8
    for (int f = 0; f < F_ / 4; ++f) {
        float4 wv = w[f];
        float4 xv = ((const float4*)xs)[f];
        acc += wv.x * xv.x + wv.y * xv.y + wv.z * xv.z + wv.w * xv.w;
    }
    Xp[b * H_ + k] = acc + fc1_b[k];
}

// ---------------- gconst = Xp @ w_ih[:, :H].T + b_ih + b_hh   (64 x 1024)
__global__ void k_gconst(const float* __restrict__ Xp, const float* __restrict__ w_ih,
                         const float* __restrict__ b_ih, const float* __restrict__ b_hh,
                         float* __restrict__ gconst) {
    __shared__ __align__(16) float xs[H_];
    int b = blockIdx.x;
    xs[threadIdx.x] = Xp[b * H_ + threadIdx.x];
    __syncthreads();
    #pragma unroll
    for (int q = 0; q < 4; ++q) {
        int j = threadIdx.x + q * 256;
        const float* w = w_ih + (size_t)j * HE;
        float acc = 0.f;
        #pragma unroll 8
        for (int k = 0; k < H_ / 4; ++k) {
            float4 wv = *(const float4*)(w + k * 4);
            float4 xv = ((const float4*)xs)[k];
            acc += wv.x * xv.x + wv.y * xv.y + wv.z * xv.z + wv.w * xv.w;
        }
        gconst[b * G4 + j] = acc + b_ih[j] + b_hh[j];
    }
}

// ---------------- gfullC = gconst + embeds[t] @ w_ih[:,H:].T in MFMA-C-frag order (bf16)
// elem (t,b,j): g4=b>>4, m=b&15 (quad=m>>2,r=m&3), w=j>>6, n_t=(j>>4)&3, l16=j&15
// addr = ((((t*4+g4)*16 + w)*4 + n_t)*64 + (m>>2)*16 + l16)*4 + (m&3)
__global__ void k_ge(const float* __restrict__ emb, const int* __restrict__ label,
                     const float* __restrict__ w_ih, const float* __restrict__ gconst,
                     unsigned short* __restrict__ gfullC) {
    __shared__ __align__(16) float es[8][E_];
    int jt = blockIdx.x, bt = blockIdx.y, t = blockIdx.z;
    for (int i = threadIdx.x; i < 8 * E_; i += 256) {
        int b8 = i / E_, e = i - b8 * E_;
        int b = bt * 8 + b8;
        int idx = (t == 0) ? START_ID : label[t * B_ + b];
        es[b8][e] = emb[(size_t)idx * E_ + e];
    }
    __syncthreads();
    int j = jt * 256 + threadIdx.x;
    const float* w = w_ih + (size_t)j * HE + H_;
    float acc[8] = {0.f, 0.f, 0.f, 0.f, 0.f, 0.f, 0.f, 0.f};
    for (int kk = 0; kk < E_ / 4; ++kk) {
        float4 wv = *(const float4*)(w + kk * 4);
        #pragma unroll
        for (int b8 = 0; b8 < 8; ++b8) {
            float4 ev = *(const float4*)(&es[b8][kk * 4]);
            acc[b8] += wv.x * ev.x + wv.y * ev.y + wv.z * ev.z + wv.w * ev.w;
        }
    }
    int g4 = bt >> 1, q0 = (bt & 1) * 2;
    int wv_ = j >> 6, n_t = (j >> 4) & 3, l16 = j & 15;
    unsigned short pk[8];
    #pragma unroll
    for (int b8 = 0; b8 < 8; ++b8)
        pk[b8] = f_to_bf16bits(acc[b8] + gconst[(bt * 8 + b8) * G4 + j]);
    size_t base = ((((size_t)(t * 4 + g4) * 16 + wv_) * 4 + n_t) * 64 + l16) * 4;
    uint2 s0, s1;
    s0.x = (unsigned)pk[0] | ((unsigned)pk[1] << 16);
    s0.y = (unsigned)pk[2] | ((unsigned)pk[3] << 16);
    s1.x = (unsigned)pk[4] | ((unsigned)pk[5] << 16);
    s1.y = (unsigned)pk[6] | ((unsigned)pk[7] << 16);
    *(uint2*)(gfullC + base + (size_t)q0 * 64) = s0;          // quad q0   (b8 0..3)
    *(uint2*)(gfullC + base + (size_t)(q0 + 1) * 64) = s1;    // quad q0+1 (b8 4..7)
}

// ---------------- LSTM recurrence: 4 independent blocks (16 batch rows each),
// h in LDS, w_hh streamed from L2 as prepacked B-frags, MFMA per step. No grid sync.
__global__ __launch_bounds__(1024) void k_lstm(const unsigned short* __restrict__ gfullC,
                                               const unsigned short* __restrict__ wbf,
                                               __hip_bfloat16* __restrict__ Hs) {
    int g4 = blockIdx.x;
    int tid = threadIdx.x;
    int w = tid >> 6, lane = tid & 63;
    int l16 = lane & 15, quad = lane >> 4;
    __shared__ unsigned short hA[16 * HP];    // h in A-frag layout [m][k], pitch 264
    __shared__ float gs[16 * GP];             // gate pre-acts [m][j], pitch 1028

    // zero hA (h(-1) = 0)
    for (int i = tid; i < 16 * HP; i += 1024) hA[i] = 0;

    int bl = tid >> 6;                         // gate-math: batch row = wave id
    int u4 = (tid & 63) * 4;                   // 4 hidden units per thread
    f32x4 c = {0.f, 0.f, 0.f, 0.f};

    const unsigned short* hap = hA + l16 * HP + quad * 8;
    __syncthreads();

    for (int t = 0; t < S_; ++t) {
        // C-init from gfullC (coalesced 8B/lane)
        const unsigned short* gp =
            gfullC + ((((size_t)(t * 4 + g4) * 16 + w) * 4 + 0) * 64 + lane) * 4;
        f32x4 acc[4];
        #pragma unroll
        for (int n_t = 0; n_t < 4; ++n_t) {
            uint2 cp = *(const uint2*)(gp + (size_t)n_t * 256);
            acc[n_t][0] = bf16bits_to_f(cp.x << 16);
            acc[n_t][1] = bf16bits_to_f(cp.x & 0xffff0000u);
            acc[n_t][2] = bf16bits_to_f(cp.y << 16);
            acc[n_t][3] = bf16bits_to_f(cp.y & 0xffff0000u);
        }
        // MFMA: A from LDS, B streamed (L2-hot, coalesced 1KB/instr)
        const unsigned short* wp = wbf + ((size_t)(w * 4) * 8) * 512 + lane * 8;
        #pragma unroll
        for (int k_t = 0; k_t < 8; ++k_t) {
            bf16x8 a = *(const bf16x8*)(hap + k_t * 32);
            #pragma unroll
            for (int n_t = 0; n_t < 4; ++n_t) {
                bf16x8 b = *(const bf16x8*)(wp + ((size_t)(n_t * 8 + k_t)) * 512);
                acc[n_t] = __builtin_amdgcn_mfma_f32_16x16x32_bf16(a, b, acc[n_t], 0, 0, 0);
            }
        }
        // write gates to LDS
        #pragma unroll
        for (int n_t = 0; n_t < 4; ++n_t)
            #pragma unroll
            for (int r = 0; r < 4; ++r)
                gs[(quad * 4 + r) * GP + w * 64 + n_t * 16 + l16] = acc[n_t][r];
        __syncthreads();

        // gate math: wave bl handles batch row bl; thread owns hidden u4..u4+3
        f32x4 gi = *(const f32x4*)(gs + bl * GP + u4);
        f32x4 gf = *(const f32x4*)(gs + bl * GP + 256 + u4);
        f32x4 gg = *(const f32x4*)(gs + bl * GP + 512 + u4);
        f32x4 go = *(const f32x4*)(gs + bl * GP + 768 + u4);
        unsigned short hb[4];
        #pragma unroll
        for (int r = 0; r < 4; ++r) {
            float ig = sigm(gi[r]);
            float fg = sigm(gf[r]);
            float g_ = tanh_fast(gg[r]);
            float og = sigm(go[r]);
            c[r] = fg * c[r] + ig * g_;
            hb[r] = f_to_bf16bits(og * tanh_fast(c[r]));
        }
        uint2 hp2;
        hp2.x = (unsigned)hb[0] | ((unsigned)hb[1] << 16);
        hp2.y = (unsigned)hb[2] | ((unsigned)hb[3] << 16);
        *(uint2*)(hA + bl * HP + u4) = hp2;                              // next-step A
        *(uint2*)((unsigned short*)Hs + ((size_t)(t * 64 + g4 * 16 + bl)) * H_ + u4) = hp2;
        __syncthreads();
    }
}

// ---------------- logits = Hs @ fc2_w.T + fc2_b -> out[b][t+1][v]  (bf16 MFMA)
// epilogue: stage C in LDS (pitch 132), write coalesced float4 rows + fused bias
__global__ __launch_bounds__(256) void k_gemm(const unsigned short* __restrict__ A,   // MPAD x 256 bf16
                                              const unsigned short* __restrict__ Bw,  // NPAD x 256 bf16
                                              const float* __restrict__ bias,
                                              float* __restrict__ out) {
    __shared__ float ts[128 * 132];
    int nt = blockIdx.x, mt = blockIdx.y;
    int w = threadIdx.x >> 6, lane = threadIdx.x & 63;
    int l16 = lane & 15, quad = lane >> 4;
    int m0l = (w >> 1) * 64;
    int n0l = (w & 1) * 64;
    f32x4 acc[4][4] = {};
    const unsigned short* Ap = A + (size_t)(mt * 128 + m0l + l16) * H_ + quad * 8;
    const unsigned short* Bp = Bw + (size_t)(nt * 128 + n0l + l16) * H_ + quad * 8;
    #pragma unroll
    for (int k = 0; k < H_; k += 32) {
        bf16x8 a[4], bb[4];
        #pragma unroll
        for (int i = 0; i < 4; ++i) {
            a[i]  = *(const bf16x8*)(Ap + (size_t)i * 16 * H_ + k);
            bb[i] = *(const bf16x8*)(Bp + (size_t)i * 16 * H_ + k);
        }
        #pragma unroll
        for (int i = 0; i < 4; ++i)
            #pragma unroll
            for (int jn = 0; jn < 4; ++jn)
                acc[i][jn] = __builtin_amdgcn_mfma_f32_16x16x32_bf16(a[i], bb[jn], acc[i][jn], 0, 0, 0);
    }
    #pragma unroll
    for (int i = 0; i < 4; ++i)
        #pragma unroll
        for (int jn = 0; jn < 4; ++jn)
            #pragma unroll
            for (int r = 0; r < 4; ++r)
                ts[(m0l + i * 16 + quad * 4 + r) * 132 + n0l + jn * 16 + l16] = acc[i][jn][r];
    __syncthreads();
    int row8 = threadIdx.x >> 5, col4 = (threadIdx.x & 31) * 4;
    int n = nt * 128 + col4;
    if (n < V_) {
        float4 bv = *(const float4*)(bias + n);
        #pragma unroll
        for (int it = 0; it < 16; ++it) {
            int ml = it * 8 + row8;
            int m = mt * 128 + ml;
            if (m < S_ * B_) {
                int t = m >> 6, b = m & 63;
                float4 v = *(const float4*)(ts + ml * 132 + col4);
                v.x += bv.x; v.y += bv.y; v.z += bv.z; v.w += bv.w;
                *(float4*)(out + ((size_t)b * T_ + t + 1) * V_ + n) = v;
            }
        }
    }
}

// ---------------- in-place log_softmax over V per (t,b) row — online, float4
__global__ void k_lsm(float* __restrict__ out) {
    __shared__ float rmx[256], rsum[256];
    int m = blockIdx.x;                   // 0..1983, m = t*64+b
    int t = m >> 6, b = m & 63;
    float* row = out + ((size_t)b * T_ + t + 1) * V_;
    int tid = threadIdx.x;
    float mx = -1e30f, sum = 0.f;
    for (int v4 = tid; v4 < V_ / 4; v4 += 256) {
        float4 x = ((const float4*)row)[v4];
        float m4 = fmaxf(fmaxf(x.x, x.y), fmaxf(x.z, x.w));
        if (m4 > mx) { sum *= __expf(mx - m4); mx = m4; }
        sum += __expf(x.x - mx) + __expf(x.y - mx) + __expf(x.z - mx) + __expf(x.w - mx);
    }
    rmx[tid] = mx; rsum[tid] = sum;
    __syncthreads();
    for (int s = 128; s > 0; s >>= 1) {
        if (tid < s) {
            float ma = rmx[tid], mb = rmx[tid + s];
            float sa = rsum[tid], sb = rsum[tid + s];
            float mm = fmaxf(ma, mb);
            rmx[tid] = mm;
            rsum[tid] = sa * __expf(ma - mm) + sb * __expf(mb - mm);
        }
        __syncthreads();
    }
    float lse = rmx[0] + logf(rsum[0]);
    for (int v4 = tid; v4 < V_ / 4; v4 += 256) {
        float4 x = ((const float4*)row)[v4];
        x.x -= lse; x.y -= lse; x.z -= lse; x.w -= lse;
        ((float4*)row)[v4] = x;
    }
}

extern "C" void kernel_launch(void* const* d_in, const int* in_sizes, int n_in,
                              void* d_out, int out_size, void* d_ws, size_t ws_size,
                              hipStream_t stream) {
    const float* X      = (const float*)d_in[0];
    const float* emb    = (const float*)d_in[1];
    const float* fc1_w  = (const float*)d_in[2];
    const float* fc1_b  = (const float*)d_in[3];
    const float* w_ih   = (const float*)d_in[4];
    const float* w_hh   = (const float*)d_in[5];
    const float* b_ih   = (const float*)d_in[6];
    const float* b_hh   = (const float*)d_in[7];
    const float* fc2_w  = (const float*)d_in[8];
    const float* fc2_b  = (const float*)d_in[9];
    const int*   label  = (const int*)d_in[10];
    float* out = (float*)d_out;

    char* ws = (char*)d_ws;
    float*          Xp     = (float*)(ws);                        // 65,536
    float*          gconst = (float*)(ws + 65536);                // 262,144
    unsigned short* gfullC = (unsigned short*)(ws + 327680);      // 31*4096*... = 4,063,232
    __hip_bfloat16* Hs     = (__hip_bfloat16*)(ws + 4390912);     // 2048*256*2 = 1,048,576
    __hip_bfloat16* fc2bf  = (__hip_bfloat16*)(ws + 5439488);     // 10112*256*2 = 5,177,344
    unsigned short* wbf    = (unsigned short*)(ws + 10616832);    // 512 KB
    // total = 11,141,120 bytes

    k_prep  <<<NPAD, 256, 0, stream>>>(fc2_w, w_hh, fc2bf, Hs, wbf, out);
    k_xp    <<<B_, 256, 0, stream>>>(X, fc1_w, fc1_b, Xp);
    k_gconst<<<B_, 256, 0, stream>>>(Xp, w_ih, b_ih, b_hh, gconst);
    k_ge    <<<dim3(4, 8, S_), 256, 0, stream>>>(emb, label, w_ih, gconst, gfullC);
    k_lstm  <<<4, 1024, 0, stream>>>(gfullC, wbf, Hs);
    k_gemm  <<<dim3(NPAD / 128, MPAD / 128), 256, 0, stream>>>((const unsigned short*)Hs,
                                                              (const unsigned short*)fc2bf, fc2_b, out);
    k_lsm   <<<S_ * B_, 256, 0, stream>>>(out);
}